// Round 9
// baseline (312.678 us; speedup 1.0000x reference)
//
#include <hip/hip_runtime.h>
#include <math.h>

// B=8, L=32, H=1024, N=32
// ws layout (floats):
#define NODE_OFF   0          // 8192*32
#define CN_OFF     262144     // 8192*32 (diag rows: chart_diag + 2*node)
#define SPAN_OFF   524288     // 8192
#define D_OFF      532480     // 256*32
#define RBF_OFF    540672     // 32768 halfs: frag-order bf16 exp(rules), q-major k
#define PART_OFF   557056     // 4*262144
#define PARTS_OFF  1605632    // 4*8192

typedef short bf16x8 __attribute__((ext_vector_type(8)));
typedef float f32x16 __attribute__((ext_vector_type(16)));

union BFU { unsigned u[4]; bf16x8 v; };

__device__ inline short f2bf(float f) {            // RNE f32->bf16
  union { float f; unsigned u; } v; v.f = f;
  unsigned r = (v.u + 0x7FFFu + ((v.u >> 16) & 1u)) >> 16;
  return (short)r;
}
__device__ __forceinline__ unsigned short hubf(float f) {  // half-up round
  return (unsigned short)((__float_as_uint(f) + 0x8000u) >> 16);
}
__device__ __forceinline__ float bfup(unsigned short u) {
  return __uint_as_float(((unsigned)u) << 16);
}
__device__ __forceinline__ unsigned pk2bf(float lo, float hi) {
  unsigned r;
  asm("v_cvt_pk_bf16_f32 %0, %1, %2" : "=v"(r) : "v"(lo), "v"(hi));
  return r;
}

// Fused front kernel, 896 blocks x 256:
//  0..511: node split-K GEMM   512..767: posnode+D   768..895: Rbf swizzle
__global__ __launch_bounds__(256) void k_pre(
    const float* __restrict__ ph, const float* __restrict__ Wn,
    const float* __restrict__ Ws, const float* __restrict__ sh,
    const float* __restrict__ Wp, const float* __restrict__ bp,
    const float* __restrict__ pmask, const float* __restrict__ pu,
    const float* __restrict__ pum, const float* __restrict__ rs,
    const float* __restrict__ rm, float* __restrict__ part,
    float* __restrict__ partS, float* __restrict__ D,
    unsigned short* __restrict__ Rbf) {
  __shared__ float smem[12672];
  int t = threadIdx.x;
  int bid = blockIdx.x;
  if (bid >= 768) {   // ---- Rbf: frag-order bf16 exp(masked rules), k''=q*32+p ----
    int idx = ((bid - 768) << 8) + t;        // [kst(64)][lane(64)][r(8)]
    int kst = idx >> 9, ln = (idx >> 3) & 63, r = idx & 7;
    int a = ln & 31;
    int kp = kst * 16 + ((ln >> 5) << 3) + r;          // k'' index
    int ri = a * 1024 + ((kp & 31) << 5) + (kp >> 5);  // rule[a][p][q], p=k''&31
    float v = __expf(rs[ri] + (rm[ri] - 1.0f) * 1e10f);
    Rbf[idx] = (unsigned short)f2bf(v);
    return;
  }
  if (bid >= 512) {   // ---- posnode + D ----
    float* rowl = smem;
    float* partl = smem + 1024;
    float* posn = smem + 1288;
    int row = bid - 512;
#pragma unroll
    for (int k = 0; k < 4; ++k) rowl[t + 256 * k] = sh[row * 1024 + t + 256 * k];
    __syncthreads();
    int c = t & 31, seg = t >> 5;
    float pacc = 0.f;
    for (int hh = 0; hh < 128; ++hh)
      pacc += rowl[seg * 128 + hh] * Wp[(seg * 128 + hh) * 32 + c];
    partl[seg * 33 + c] = pacc;
    __syncthreads();
    if (t < 32) {
      float s = 0.f;
#pragma unroll
      for (int k = 0; k < 8; ++k) s += partl[k * 33 + t];
      posn[t] = s + bp[t] + (pmask[t] - 1.0f) * 1e10f;
    }
    __syncthreads();
    if (t < 32) {
      float mq = posn[t];
#pragma unroll
      for (int m = 16; m >= 1; m >>= 1) mq = fmaxf(mq, __shfl_xor(mq, m, 32));
      float sum = 0.f;
#pragma unroll 8
      for (int q = 0; q < 32; ++q)
        sum += __expf(pu[t * 32 + q] + (pum[t * 32 + q] - 1.0f) * 1e15f + posn[q] - mq);
      D[row * 32 + t] = mq + __logf(sum);
    }
    return;
  }
  // ---- node split-K GEMM ----
  float (*A)[132] = (float(*)[132])smem;
  float (*Wl)[32] = (float(*)[32])(smem + 8448);
  float* Wsl = smem + 12544;
  int rg = bid >> 2;
  int s = bid & 3;
  int row0 = rg * 64;
  int h0 = s * 256;
  int tr = t >> 3, tc = t & 7;
  int r0 = tr * 2;
  int c = tc * 4;
  float acc[8] = {0.f, 0.f, 0.f, 0.f, 0.f, 0.f, 0.f, 0.f};
  float sp0 = 0.f, sp1 = 0.f;
  for (int hc = 0; hc < 2; ++hc) {
    int hb = h0 + hc * 128;
#pragma unroll
    for (int k = 0; k < 32; ++k) {
      int f = t + 256 * k;
      int rr = f >> 7, hh = f & 127;
      A[rr][hh] = ph[(row0 + rr) * 1024 + hb + hh];
    }
#pragma unroll
    for (int k = 0; k < 16; ++k) {
      int f = t + 256 * k;
      int hh = f >> 5, cc = f & 31;
      Wl[hh][cc] = Wn[(hb + hh) * 32 + cc];
    }
    if (t < 128) Wsl[t] = Ws[hb + t];
    __syncthreads();
#pragma unroll 2
    for (int h = 0; h < 128; ++h) {
      float a0 = A[r0][h], a1 = A[r0 + 1][h];
      float4 w = *(const float4*)&Wl[h][c];
      acc[0] += a0 * w.x; acc[1] += a0 * w.y; acc[2] += a0 * w.z; acc[3] += a0 * w.w;
      acc[4] += a1 * w.x; acc[5] += a1 * w.y; acc[6] += a1 * w.z; acc[7] += a1 * w.w;
      if (tc == 0) { float wv = Wsl[h]; sp0 += a0 * wv; sp1 += a1 * wv; }
    }
    __syncthreads();
  }
  int row = row0 + r0;
  float* po = part + s * 262144;
  *(float4*)&po[row * 32 + c] = make_float4(acc[0], acc[1], acc[2], acc[3]);
  *(float4*)&po[(row + 1) * 32 + c] = make_float4(acc[4], acc[5], acc[6], acc[7]);
  if (tc == 0) {
    partS[s * 8192 + row] = sp0;
    partS[s * 8192 + row + 1] = sp1;
  }
}

__global__ __launch_bounds__(256) void k_node_reduce(
    const float* __restrict__ part, const float* __restrict__ partS,
    const float* __restrict__ bn, const float* __restrict__ bs,
    const float* __restrict__ D, float* __restrict__ node,
    float* __restrict__ cng, float* __restrict__ span) {
  int t = threadIdx.x;
  int row = blockIdx.x * 8 + (t >> 5);
  int c = t & 31;
  float v = bn[c];
#pragma unroll
  for (int s = 0; s < 4; ++s) v += part[s * 262144 + row * 32 + c];
  node[row * 32 + c] = v;
  int l = (row >> 5) & 31, m = row & 31;
  if (l == m)
    cng[row * 32 + c] = v + D[(row >> 5) * 32 + c] + v;   // chart_diag + node
  if (c == 0) {
    float sp = bs[0];
#pragma unroll
    for (int s = 0; s < 4; ++s) sp += partS[s * 8192 + row];
    span[row] = sp;
  }
}

// One block per batch. Chart held in LDS as bf16 X = exp(cn - rowmax), TWICE:
//  XtF [a][row=start][pos=end-start]  (left/B operand: aligned pure loads)
//  YtR [a][row=end][pos=end-start]    (right/A operand: scl-weighted)
// All OOB/pad slots read 0.0 (arrays zero-initialized) -> zero-padded K exact.
// LDS (163,520 B):
//  Sb u16 32x1026 @0      slots f32[2048] @65664  Tscl/cnS f32 @73856 (4224)
//  maxv f32[640] @78080   G @80640  XB @80768  YB @80896
//  XtF u16 32x644 @81024  YtR u16 32x644 @122240  pad @163456
__global__ __launch_bounds__(1024) void k_chain4(
    const float* __restrict__ node, const float* __restrict__ span,
    const float* __restrict__ cng, const unsigned short* __restrict__ Rbf,
    const int* __restrict__ sm, const float* __restrict__ rootm,
    float* __restrict__ out) {
  extern __shared__ char lds[];
  unsigned short* Sb = (unsigned short*)lds;
  float* slots = (float*)(lds + 65664);
  float* Tscl = (float*)(lds + 73856);
  float* cnS = Tscl;                       // aliased (disjoint lifetimes)
  float* maxv = (float*)(lds + 78080);
  float* G = (float*)(lds + 80640);
  int* XB = (int*)(lds + 80768);
  int* YB = (int*)(lds + 80896);
  unsigned short* XtF = (unsigned short*)(lds + 81024);
  unsigned short* YtR = (unsigned short*)(lds + 122240);
  const int t = threadIdx.x;
  const int b = blockIdx.x;
  const int w = t >> 6, ln = t & 63;
  const int pq = ln & 31, hi = ln >> 5, jb = hi << 3;
  const int rowB = b * 32;
  const int a_o = (w & 3) + ((w >> 2) << 3) + (hi << 2);  // C/D row (reg=w)
  const int c_o = pq;                                      // C/D col (cell)

  // ---- zero-init Sb + XtF/YtR (NaN-proof: every readable slot finite) ----
  {
    unsigned* z0 = (unsigned*)lds;                  // Sb: 65664 B = 16416 words
    for (int idx = t; idx < 16416; idx += 1024) z0[idx] = 0;
    unsigned* z1 = (unsigned*)(lds + 81024);        // XtF+YtR: 82432 B = 20608 w
    for (int idx = t; idx < 20608; idx += 1024) z1[idx] = 0;
  }
  // ---- row-base tables ----
  if (t < 32) {
    int s = 0;
    for (int u = 0; u < t; ++u) s += (39 - u) & ~7;    // ceil((32-u)/8)*8
    XB[t] = s;
  } else if (t < 64) {
    int e = t - 32, s = 0;
    for (int f = 0; f < e; ++f) s += (f + 8) & ~7;     // ceil((f+1)/8)*8
    YB[e] = s;
  }
  // diagonal global prefetch overlaps the init work above
  {
    int l = t >> 5, a = t & 31;
    float dv = cng[((rowB + l) * 32 + l) * 32 + a];
    __syncthreads();                                 // tables + zero done
    float m = dv;
#pragma unroll
    for (int s = 16; s >= 1; s >>= 1) m = fmaxf(m, __shfl_xor(m, s, 32));
    unsigned short xb = hubf(__expf(dv - m));
    XtF[a * 644 + XB[l]] = xb;
    YtR[a * 644 + YB[l]] = xb;
    if (a == 0) maxv[XB[l]] = m;
  }
  __syncthreads();

  for (int i = 1; i < 32; ++i) {
    const int nT = 32 - i;
    // ---- out-phase global prefetch ----
    float nv = 0.f, sv = 0.f;
    if (c_o < nT) {
      int gr = (rowB + c_o) * 32 + (c_o + i);
      nv = node[gr * 32 + a_o];
      sv = span[gr];
    }
    // ---- P1: Tscl[c][k=j] + G[c] ----
    {
      int c = t >> 5, j = t & 31;
      float gj = -3.0e38f;
      if (c < nT && j < i)
        gj = maxv[XB[c] + j] + maxv[XB[c + j + 1] + (i - 1 - j)];
      float gm = gj;
#pragma unroll
      for (int s = 16; s >= 1; s >>= 1) gm = fmaxf(gm, __shfl_xor(gm, s, 32));
      if (c < nT) {
        Tscl[(c << 5) + j] = (j < i) ? __expf(gj - gm) : 0.f;
        if (j == 0) G[c] = gm;
      }
    }
    __syncthreads();
    // ---- P2: wave w -> cells w, 16+w; S^T = sum_k (scl*Xr) (x) Xl ----
#pragma unroll 1
    for (int half = 0; half < 2; ++half) {
      int cg = (half << 4) + w;
      if (cg >= nT) break;                 // wave-uniform
      int e = cg + i;
      int ybe = YB[e];
      f32x16 Sacc = {};
#pragma unroll
      for (int kk = 0; kk < 2; ++kk) {
        if (kk == 1 && i <= 16) break;
        int K0 = kk << 4;
        // A: scl[k] * Xr (reversed positions), k = K0+jb+r
        int bi = pq * 644 + ybe + (i - 1) - K0 - jb;
        const float* sclp = Tscl + (cg << 5) + K0 + jb;
        float av[8];
#pragma unroll
        for (int r = 0; r < 8; ++r)
          av[r] = bfup(YtR[bi - r]) * sclp[r];
        BFU ua, ub;
#pragma unroll
        for (int r2 = 0; r2 < 4; ++r2)
          ua.u[r2] = pk2bf(av[2 * r2], av[2 * r2 + 1]);
        // B: Xl forward-aligned pure load
        int xi = pq * 644 + XB[cg] + K0 + jb;
        uint2 b0 = *(const uint2*)(XtF + xi);
        uint2 b1 = *(const uint2*)(XtF + xi + 4);
        ub.u[0] = b0.x; ub.u[1] = b0.y; ub.u[2] = b1.x; ub.u[3] = b1.y;
        Sacc = __builtin_amdgcn_mfma_f32_32x32x16_bf16(ua.v, ub.v, Sacc, 0, 0, 0);
      }
      // store S^T bf16 swizzled; C/D: col=pq(=p), row q=(rr&3)+8*(rr>>2)+4*hi
      unsigned short* sb = Sb + cg * 1026;
#pragma unroll
      for (int rr = 0; rr < 16; ++rr) {
        int q = (rr & 3) + ((rr >> 2) << 3) + (hi << 2);
        int wd = (((q << 4) + (pq >> 1)) ^ (((pq >> 3) & 1) << 4)) ^ (((q >> 2) & 1) << 2);
        sb[(wd << 1) + (pq & 1)] = hubf(Sacc[rr]);
      }
    }
    __syncthreads();
    // ---- P3: inner = R * S', 32 cells wide, 2-wave k-split ----
    if (w < 2) {
      f32x16 C0 = {}, C1 = {};
#pragma unroll
      for (int tt = 0; tt < 32; ++tt) {
        int kst = (w << 5) + tt;
        bf16x8 ra = *(const bf16x8*)(Rbf + (kst << 9) + (ln << 3));
        int ko = (kst << 1) + hi;
        int qr = ko >> 2, o = ko & 3;
        int wd = (((qr << 4) + (o << 2)) ^ ((o & 1) << 4)) ^ (((qr >> 2) & 1) << 2);
        const unsigned short* sp = Sb + pq * 1026 + (wd << 1);
        BFU ub;
        ub.u[0] = *(const unsigned*)sp;
        ub.u[1] = *(const unsigned*)(sp + 2);
        ub.u[2] = *(const unsigned*)(sp + 4);
        ub.u[3] = *(const unsigned*)(sp + 6);
        if (tt & 1) C1 = __builtin_amdgcn_mfma_f32_32x32x16_bf16(ra, ub.v, C1, 0, 0, 0);
        else        C0 = __builtin_amdgcn_mfma_f32_32x32x16_bf16(ra, ub.v, C0, 0, 0, 0);
      }
      float* sl = slots + (w << 10);
#pragma unroll
      for (int rr = 0; rr < 16; ++rr) sl[(rr << 6) + ln] = C0[rr] + C1[rr];
    }
    __syncthreads();
    // ---- out: raw cn -> cnS (f32) ----
    if (c_o < nT) {
      float pt = slots[(w << 6) + ln] + slots[1024 + (w << 6) + ln];
      cnS[c_o * 33 + a_o] = G[c_o] + __logf(pt) + nv + nv + sv;
    }
    __syncthreads();
    // ---- renorm: X = exp(cn - rowmax) -> XtF, YtR (bf16); maxv ----
    {
      int c = t >> 5, a = t & 31;
      float val = (c < nT) ? cnS[c * 33 + a] : 0.f;
      float m = val;
#pragma unroll
      for (int s = 16; s >= 1; s >>= 1) m = fmaxf(m, __shfl_xor(m, s, 32));
      if (c < nT) {
        unsigned short xb = hubf(__expf(val - m));
        XtF[a * 644 + XB[c] + i] = xb;
        YtR[a * 644 + YB[c + i] + i] = xb;
        if (a == 0) maxv[XB[c] + i] = m;
      }
    }
    __syncthreads();
  }
  // ---- logits ----
  if (t < 32) {
    int len = 0;
#pragma unroll
    for (int l = 0; l < 32; ++l) len += sm[b * 32 + l];
    int e = len - 1;   // cell (0, e): XtF row 0, pos e
    float cv = maxv[XB[0] + e] + __logf(bfup(XtF[t * 644 + XB[0] + e])) -
               node[(rowB * 32 + e) * 32 + t];
    out[b * 32 + t] = cv + (rootm[t] - 1.0f) * 1e10f;
  }
}

extern "C" void kernel_launch(void* const* d_in, const int* in_sizes, int n_in,
                              void* d_out, int out_size, void* d_ws, size_t ws_size,
                              hipStream_t stream) {
  const float* ph    = (const float*)d_in[0];
  const float* sh    = (const float*)d_in[1];
  const int*   sm    = (const int*)  d_in[2];
  const float* Wp    = (const float*)d_in[3];
  const float* bp    = (const float*)d_in[4];
  const float* Wn    = (const float*)d_in[5];
  const float* bn    = (const float*)d_in[6];
  const float* Ws    = (const float*)d_in[7];
  const float* bs    = (const float*)d_in[8];
  const float* rs    = (const float*)d_in[9];
  const float* pu    = (const float*)d_in[10];
  const float* rootm = (const float*)d_in[11];
  const float* pm    = (const float*)d_in[12];
  const float* rm    = (const float*)d_in[13];
  const float* pum   = (const float*)d_in[14];
  float* out = (float*)d_out;

  float* ws    = (float*)d_ws;
  float* node  = ws + NODE_OFF;
  float* cng   = ws + CN_OFF;
  float* span  = ws + SPAN_OFF;
  float* D     = ws + D_OFF;
  unsigned short* Rbf = (unsigned short*)(ws + RBF_OFF);
  float* part  = ws + PART_OFF;
  float* partS = ws + PARTS_OFF;

  hipFuncSetAttribute((const void*)k_chain4,
                      hipFuncAttributeMaxDynamicSharedMemorySize, 163520);
  k_pre<<<896, 256, 0, stream>>>(ph, Wn, Ws, sh, Wp, bp, pm, pu, pum, rs, rm,
                                 part, partS, D, Rbf);
  k_node_reduce<<<1024, 256, 0, stream>>>(part, partS, bn, bs, D, node, cng, span);
  k_chain4<<<8, 1024, 163520, stream>>>(node, span, cng, Rbf, sm, rootm, out);
}

// Round 10
// 209.262 us; speedup vs baseline: 1.4942x; 1.4942x over previous
//
#include <hip/hip_runtime.h>
#include <math.h>

// B=8, L=32, H=1024, N=32
// ws layout (floats):
#define NODE_OFF   0          // 8192*32
#define CN_OFF     262144     // 8192*32 (diag rows: chart_diag + 2*node)
#define SPAN_OFF   524288     // 8192
#define D_OFF      532480     // 256*32
#define RBF_OFF    540672     // 32768 halfs: frag-order bf16 exp(rules)
#define PART_OFF   557056     // 4*262144
#define PARTS_OFF  1605632    // 4*8192

typedef short bf16x8 __attribute__((ext_vector_type(8)));
typedef float f32x16 __attribute__((ext_vector_type(16)));

union BFU { unsigned u[4]; bf16x8 v; };

__device__ inline short f2bf(float f) {            // RNE f32->bf16
  union { float f; unsigned u; } v; v.f = f;
  unsigned r = (v.u + 0x7FFFu + ((v.u >> 16) & 1u)) >> 16;
  return (short)r;
}

// Fused front kernel, 896 blocks x 256:
//  0..511: node split-K GEMM   512..767: posnode+D   768..895: Rbf swizzle
__global__ __launch_bounds__(256) void k_pre(
    const float* __restrict__ ph, const float* __restrict__ Wn,
    const float* __restrict__ Ws, const float* __restrict__ sh,
    const float* __restrict__ Wp, const float* __restrict__ bp,
    const float* __restrict__ pmask, const float* __restrict__ pu,
    const float* __restrict__ pum, const float* __restrict__ rs,
    const float* __restrict__ rm, float* __restrict__ part,
    float* __restrict__ partS, float* __restrict__ D,
    unsigned short* __restrict__ Rbf) {
  __shared__ float smem[12672];
  int t = threadIdx.x;
  int bid = blockIdx.x;
  if (bid >= 768) {   // ---- Rbf: frag-order bf16 of exp(masked rules) ----
    int idx = ((bid - 768) << 8) + t;        // [kst(64)][lane(64)][r(8)]
    int kst = idx >> 9, ln = (idx >> 3) & 63, r = idx & 7;
    int a = ln & 31;
    int kp = kst * 16 + ((ln >> 5) << 3) + r;   // k' = p*32+q
    float v = __expf(rs[a * 1024 + kp] + (rm[a * 1024 + kp] - 1.0f) * 1e10f);
    Rbf[idx] = (unsigned short)f2bf(v);
    return;
  }
  if (bid >= 512) {   // ---- posnode + D ----
    float* rowl = smem;
    float* partl = smem + 1024;
    float* posn = smem + 1288;
    int row = bid - 512;
#pragma unroll
    for (int k = 0; k < 4; ++k) rowl[t + 256 * k] = sh[row * 1024 + t + 256 * k];
    __syncthreads();
    int c = t & 31, seg = t >> 5;
    float pacc = 0.f;
    for (int hh = 0; hh < 128; ++hh)
      pacc += rowl[seg * 128 + hh] * Wp[(seg * 128 + hh) * 32 + c];
    partl[seg * 33 + c] = pacc;
    __syncthreads();
    if (t < 32) {
      float s = 0.f;
#pragma unroll
      for (int k = 0; k < 8; ++k) s += partl[k * 33 + t];
      posn[t] = s + bp[t] + (pmask[t] - 1.0f) * 1e10f;
    }
    __syncthreads();
    if (t < 32) {
      float mq = posn[t];
#pragma unroll
      for (int m = 16; m >= 1; m >>= 1) mq = fmaxf(mq, __shfl_xor(mq, m, 32));
      float sum = 0.f;
#pragma unroll 8
      for (int q = 0; q < 32; ++q)
        sum += __expf(pu[t * 32 + q] + (pum[t * 32 + q] - 1.0f) * 1e15f + posn[q] - mq);
      D[row * 32 + t] = mq + __logf(sum);
    }
    return;
  }
  // ---- node split-K GEMM (float4 staging) ----
  float (*A)[132] = (float(*)[132])smem;
  float (*Wl)[32] = (float(*)[32])(smem + 8448);
  float* Wsl = smem + 12544;
  int rg = bid >> 2;
  int s = bid & 3;
  int row0 = rg * 64;
  int h0 = s * 256;
  int tr = t >> 3, tc = t & 7;
  int r0 = tr * 2;
  int c = tc * 4;
  float acc[8] = {0.f, 0.f, 0.f, 0.f, 0.f, 0.f, 0.f, 0.f};
  float sp0 = 0.f, sp1 = 0.f;
  for (int hc = 0; hc < 2; ++hc) {
    int hb = h0 + hc * 128;
#pragma unroll
    for (int k = 0; k < 8; ++k) {          // A: 64x128 f32 = 2048 float4
      int f = t + (k << 8);
      int rr = f >> 5, c4 = f & 31;
      *(float4*)&A[rr][c4 << 2] =
          *(const float4*)&ph[(row0 + rr) * 1024 + hb + (c4 << 2)];
    }
#pragma unroll
    for (int k = 0; k < 4; ++k) {          // W: 128x32 f32 = 1024 float4
      int f = t + (k << 8);
      int hh = f >> 3, c4 = f & 7;
      *(float4*)&Wl[hh][c4 << 2] =
          *(const float4*)&Wn[(hb + hh) * 32 + (c4 << 2)];
    }
    if (t < 128) Wsl[t] = Ws[hb + t];
    __syncthreads();
#pragma unroll 2
    for (int h = 0; h < 128; ++h) {
      float a0 = A[r0][h], a1 = A[r0 + 1][h];
      float4 w = *(const float4*)&Wl[h][c];
      acc[0] += a0 * w.x; acc[1] += a0 * w.y; acc[2] += a0 * w.z; acc[3] += a0 * w.w;
      acc[4] += a1 * w.x; acc[5] += a1 * w.y; acc[6] += a1 * w.z; acc[7] += a1 * w.w;
      if (tc == 0) { float wv = Wsl[h]; sp0 += a0 * wv; sp1 += a1 * wv; }
    }
    __syncthreads();
  }
  int row = row0 + r0;
  float* po = part + s * 262144;
  *(float4*)&po[row * 32 + c] = make_float4(acc[0], acc[1], acc[2], acc[3]);
  *(float4*)&po[(row + 1) * 32 + c] = make_float4(acc[4], acc[5], acc[6], acc[7]);
  if (tc == 0) {
    partS[s * 8192 + row] = sp0;
    partS[s * 8192 + row + 1] = sp1;
  }
}

__global__ __launch_bounds__(256) void k_node_reduce(
    const float* __restrict__ part, const float* __restrict__ partS,
    const float* __restrict__ bn, const float* __restrict__ bs,
    const float* __restrict__ D, float* __restrict__ node,
    float* __restrict__ cng, float* __restrict__ span) {
  int t = threadIdx.x;
  int row = blockIdx.x * 8 + (t >> 5);
  int c = t & 31;
  float v = bn[c];
#pragma unroll
  for (int s = 0; s < 4; ++s) v += part[s * 262144 + row * 32 + c];
  node[row * 32 + c] = v;
  int l = (row >> 5) & 31, m = row & 31;
  if (l == m)
    cng[row * 32 + c] = v + D[(row >> 5) * 32 + c] + v;   // chart_diag + node
  if (c == 0) {
    float sp = bs[0];
#pragma unroll
    for (int s = 0; s < 4; ++s) sp += partS[s * 8192 + row];
    span[row] = sp;
  }
}

// One block per batch; chart as NORMALIZED X = exp(cn - rowmax) in LDS
// (transposed [symbol][cellidx], stride 529). Per stage (4 barriers):
// [prefetch + P1] B [P2 both halves] B [P3] B [out+renorm fused] B
// LDS 160704 B:
//   Xt    f32[32*529]   @0
//   Sb    32 x 2052 B   @67712    (bf16 S, XOR-swizzled)
//   slots f32[4*1056]   @133376   (cell-major, stride 33)
//   T2    int2[32][32]  @150272
//   maxv  f32[528]      @158464
//   G     f32[32]       @160576
__global__ __launch_bounds__(1024) void k_chain5(
    const float* __restrict__ node, const float* __restrict__ span,
    const float* __restrict__ cng, const unsigned short* __restrict__ Rbf,
    const int* __restrict__ sm, const float* __restrict__ rootm,
    float* __restrict__ out) {
  extern __shared__ char lds[];
  float* Xt = (float*)lds;
  char* Sb = lds + 67712;
  float* slots = (float*)(lds + 133376);
  int2* T2 = (int2*)(lds + 150272);
  float* maxv = (float*)(lds + 158464);
  float* G = (float*)(lds + 160576);
  const int t = threadIdx.x;
  const int b = blockIdx.x;
  const int w = t >> 6, ln = t & 63;
  const int pq = ln & 31, hi = ln >> 5, jb = hi << 3;
  const int rowB = b * 32;

  // ---- zero-init Xt (NaN-proof: every readable slot finite) ----
  {
    int l = t >> 5, a = t & 31;
    float dv = cng[((rowB + l) * 32 + l) * 32 + a];   // diag prefetch overlaps
    float* z = (float*)lds;
    for (int idx = t; idx < 16928; idx += 1024) z[idx] = 0.f;
    __syncthreads();
    // ---- init: diagonal cells -> X, maxv ----
    float m = dv;
#pragma unroll
    for (int s = 16; s >= 1; s >>= 1) m = fmaxf(m, __shfl_xor(m, s, 32));
    int off = l * (65 - l) / 2;
    Xt[a * 529 + off] = __expf(dv - m);
    if (a == 0) maxv[off] = m;
  }
  __syncthreads();

  for (int i = 1; i < 32; ++i) {
    const int nT = 32 - i;
    // ---- stage-top prefetches: out-phase operands (coalesced) + Rbf frags ----
    float nv = 0.f, sv = 0.f;
    {
      int cell = t >> 5;
      if (cell < nT) {
        nv = node[(rowB + cell) * 1024 + (cell + i) * 32 + (t & 31)];
        sv = span[(rowB + cell) * 32 + (cell + i)];
      }
    }
    BFU rb[8];
    if (w < 4) {
#pragma unroll
      for (int tt = 0; tt < 8; ++tt)
        rb[tt].v = *(const bf16x8*)(Rbf + (((w << 4) + tt) << 9) + (ln << 3));
    }
    // ---- P1: Tscl/rc tables + G ----
    {
      int c = t >> 5, j = t & 31;
      bool on = (c < nT) && (j < i);
      float gj = -3.0e38f; int rc = 0;
      if (on) {
        int m2 = c + j + 1;
        rc = m2 * (65 - m2) / 2 + (i - 1 - j);
        gj = maxv[c * (65 - c) / 2 + j] + maxv[rc];
      }
      float gm = gj;
#pragma unroll
      for (int s = 16; s >= 1; s >>= 1) gm = fmaxf(gm, __shfl_xor(gm, s, 32));
      if (c < nT) {
        float sc = on ? __expf(gj - gm) : 0.f;
        T2[(c << 5) + j] = make_int2(__float_as_int(sc), on ? rc : 0);
        if (j == 0) G[c] = gm;
      }
    }
    __syncthreads();
    // ---- P2: wave w -> cells w and 16+w; S = sum_j (scl*Xl) (x) Xr ----
#pragma unroll 1
    for (int half = 0; half < 2; ++half) {
      int cg = (half << 4) + w;
      if (cg >= nT) break;                 // wave-uniform
      const float* xlb = Xt + pq * 529 + cg * (65 - cg) / 2;
      const float* xrr = Xt + pq * 529;
      f32x16 Sacc = {};
#pragma unroll
      for (int kk = 0; kk < 2; ++kk) {
        if (kk == 1 && i <= 16) break;
        int j0 = (kk << 4);
        float xl[8], xr[8], sc[8];
#pragma unroll
        for (int r = 0; r < 8; ++r) {
          int2 e = T2[(cg << 5) + j0 + jb + r];
          sc[r] = __int_as_float(e.x);
          xr[r] = xrr[e.y];
          xl[r] = xlb[j0 + jb + r];
        }
        BFU ua, ub;
#pragma unroll
        for (int r2 = 0; r2 < 4; ++r2) {
          unsigned al = (unsigned short)f2bf(sc[2 * r2] * xl[2 * r2]);
          unsigned ah = (unsigned short)f2bf(sc[2 * r2 + 1] * xl[2 * r2 + 1]);
          ua.u[r2] = al | (ah << 16);
          unsigned bl = (unsigned short)f2bf(xr[2 * r2]);
          unsigned bh = (unsigned short)f2bf(xr[2 * r2 + 1]);
          ub.u[r2] = bl | (bh << 16);
        }
        Sacc = __builtin_amdgcn_mfma_f32_32x32x16_bf16(ua.v, ub.v, Sacc, 0, 0, 0);
      }
      // store S bf16, XOR-swizzled
      char* sbp = Sb + cg * 2052;
#pragma unroll
      for (int rr = 0; rr < 16; ++rr) {
        int p = (rr & 3) + ((rr >> 2) << 3) + (hi << 2);
        int wd = (((p << 4) + (pq >> 1)) ^ (((pq >> 3) & 1) << 4)) ^ (((p >> 2) & 1) << 2);
        *(unsigned short*)(sbp + wd * 4 + ((pq & 1) << 1)) = (unsigned short)f2bf(Sacc[rr]);
      }
    }
    __syncthreads();
    // ---- P3: inner = R * S, 32 cells wide, 4-wave k-split; Rbf from regs ----
    if (w < 4) {
      BFU rb2[8];
#pragma unroll
      for (int tt = 0; tt < 8; ++tt)
        rb2[tt].v = *(const bf16x8*)(Rbf + (((w << 4) + 8 + tt) << 9) + (ln << 3));
      f32x16 C0 = {}, C1 = {};
#pragma unroll
      for (int tt = 0; tt < 16; ++tt) {
        int kst = (w << 4) + tt;
        int ko = (kst << 1) + hi;
        int p = ko >> 2, o = ko & 3;
        int wd = (((p << 4) + (o << 2)) ^ ((o & 1) << 4)) ^ (((p >> 2) & 1) << 2);
        const char* sp = Sb + pq * 2052 + wd * 4;
        BFU ub;
        ub.u[0] = *(const unsigned*)sp;
        ub.u[1] = *(const unsigned*)(sp + 4);
        ub.u[2] = *(const unsigned*)(sp + 8);
        ub.u[3] = *(const unsigned*)(sp + 12);
        bf16x8 ra = (tt < 8) ? rb[tt].v : rb2[tt - 8].v;
        if (tt & 1) C1 = __builtin_amdgcn_mfma_f32_32x32x16_bf16(ra, ub.v, C1, 0, 0, 0);
        else        C0 = __builtin_amdgcn_mfma_f32_32x32x16_bf16(ra, ub.v, C0, 0, 0, 0);
      }
      // store cell-major (stride 33): value(lane,rr) = (a=crow, cell=pq)
      float* sl = slots + w * 1056;
#pragma unroll
      for (int rr = 0; rr < 16; ++rr) {
        int arow = (rr & 3) + ((rr >> 2) << 3) + (hi << 2);
        sl[pq * 33 + arow] = C0[rr] + C1[rr];
      }
    }
    __syncthreads();
    // ---- out + renorm fused: thread (cell=t>>5, a=t&31) ----
    {
      int cell = t >> 5, a = t & 31;
      if (cell < nT) {
        int so = cell * 33 + a;
        float pt = slots[so] + slots[1056 + so] + slots[2112 + so] + slots[3168 + so];
        float cnv = G[cell] + __logf(pt) + nv + nv + sv;   // chart + node
        float m = cnv;
#pragma unroll
        for (int s = 16; s >= 1; s >>= 1) m = fmaxf(m, __shfl_xor(m, s, 32));
        int ix = cell * (65 - cell) / 2 + i;
        Xt[a * 529 + ix] = __expf(cnv - m);
        if (a == 0) maxv[ix] = m;
      }
    }
    __syncthreads();
  }
  // ---- logits ----
  if (t < 32) {
    int len = 0;
#pragma unroll
    for (int l = 0; l < 32; ++l) len += sm[b * 32 + l];
    int e = len - 1;   // cell (0, e) has triangular index e
    float cv = maxv[e] + __logf(Xt[t * 529 + e]) - node[(rowB * 32 + e) * 32 + t];
    out[b * 32 + t] = cv + (rootm[t] - 1.0f) * 1e10f;
  }
}

extern "C" void kernel_launch(void* const* d_in, const int* in_sizes, int n_in,
                              void* d_out, int out_size, void* d_ws, size_t ws_size,
                              hipStream_t stream) {
  const float* ph    = (const float*)d_in[0];
  const float* sh    = (const float*)d_in[1];
  const int*   sm    = (const int*)  d_in[2];
  const float* Wp    = (const float*)d_in[3];
  const float* bp    = (const float*)d_in[4];
  const float* Wn    = (const float*)d_in[5];
  const float* bn    = (const float*)d_in[6];
  const float* Ws    = (const float*)d_in[7];
  const float* bs    = (const float*)d_in[8];
  const float* rs    = (const float*)d_in[9];
  const float* pu    = (const float*)d_in[10];
  const float* rootm = (const float*)d_in[11];
  const float* pm    = (const float*)d_in[12];
  const float* rm    = (const float*)d_in[13];
  const float* pum   = (const float*)d_in[14];
  float* out = (float*)d_out;

  float* ws    = (float*)d_ws;
  float* node  = ws + NODE_OFF;
  float* cng   = ws + CN_OFF;
  float* span  = ws + SPAN_OFF;
  float* D     = ws + D_OFF;
  unsigned short* Rbf = (unsigned short*)(ws + RBF_OFF);
  float* part  = ws + PART_OFF;
  float* partS = ws + PARTS_OFF;

  hipFuncSetAttribute((const void*)k_chain5,
                      hipFuncAttributeMaxDynamicSharedMemorySize, 160704);
  k_pre<<<896, 256, 0, stream>>>(ph, Wn, Ws, sh, Wp, bp, pm, pu, pum, rs, rm,
                                 part, partS, D, Rbf);
  k_node_reduce<<<1024, 256, 0, stream>>>(part, partS, bn, bs, D, node, cng, span);
  k_chain5<<<8, 1024, 160704, stream>>>(node, span, cng, Rbf, sm, rootm, out);
}

// Round 11
// 170.729 us; speedup vs baseline: 1.8314x; 1.2257x over previous
//
#include <hip/hip_runtime.h>
#include <math.h>

// B=8, L=32, H=1024, N=32
// ws layout (floats):
#define NODE_OFF   0          // 8192*32
#define CN_OFF     262144     // 8192*32 (diag rows: chart_diag + 2*node)
#define SPAN_OFF   524288     // 8192
#define D_OFF      532480     // 256*32
#define RBF_OFF    540672     // 32768 halfs: frag-order bf16 exp(rules)
#define PART_OFF   557056     // 4*262144
#define PARTS_OFF  1605632    // 4*8192

typedef short bf16x8 __attribute__((ext_vector_type(8)));
typedef float f32x16 __attribute__((ext_vector_type(16)));

union BFU { unsigned u[4]; bf16x8 v; };

__device__ inline short f2bf(float f) {            // RNE f32->bf16
  union { float f; unsigned u; } v; v.f = f;
  unsigned r = (v.u + 0x7FFFu + ((v.u >> 16) & 1u)) >> 16;
  return (short)r;
}

// Fused front kernel, 896 blocks x 256:
//  0..511: node split-K GEMM   512..767: posnode+D   768..895: Rbf swizzle
__global__ __launch_bounds__(256) void k_pre(
    const float* __restrict__ ph, const float* __restrict__ Wn,
    const float* __restrict__ Ws, const float* __restrict__ sh,
    const float* __restrict__ Wp, const float* __restrict__ bp,
    const float* __restrict__ pmask, const float* __restrict__ pu,
    const float* __restrict__ pum, const float* __restrict__ rs,
    const float* __restrict__ rm, float* __restrict__ part,
    float* __restrict__ partS, float* __restrict__ D,
    unsigned short* __restrict__ Rbf) {
  __shared__ float smem[12672];
  int t = threadIdx.x;
  int bid = blockIdx.x;
  if (bid >= 768) {   // ---- Rbf: frag-order bf16 of exp(masked rules) ----
    int idx = ((bid - 768) << 8) + t;        // [kst(64)][lane(64)][r(8)]
    int kst = idx >> 9, ln = (idx >> 3) & 63, r = idx & 7;
    int a = ln & 31;
    int kp = kst * 16 + ((ln >> 5) << 3) + r;   // k' = p*32+q
    float v = __expf(rs[a * 1024 + kp] + (rm[a * 1024 + kp] - 1.0f) * 1e10f);
    Rbf[idx] = (unsigned short)f2bf(v);
    return;
  }
  if (bid >= 512) {   // ---- posnode + D ----
    float* rowl = smem;
    float* partl = smem + 1024;
    float* posn = smem + 1288;
    int row = bid - 512;
#pragma unroll
    for (int k = 0; k < 4; ++k) rowl[t + 256 * k] = sh[row * 1024 + t + 256 * k];
    __syncthreads();
    int c = t & 31, seg = t >> 5;
    float pacc = 0.f;
    for (int hh = 0; hh < 128; ++hh)
      pacc += rowl[seg * 128 + hh] * Wp[(seg * 128 + hh) * 32 + c];
    partl[seg * 33 + c] = pacc;
    __syncthreads();
    if (t < 32) {
      float s = 0.f;
#pragma unroll
      for (int k = 0; k < 8; ++k) s += partl[k * 33 + t];
      posn[t] = s + bp[t] + (pmask[t] - 1.0f) * 1e10f;
    }
    __syncthreads();
    if (t < 32) {
      float mq = posn[t];
#pragma unroll
      for (int m = 16; m >= 1; m >>= 1) mq = fmaxf(mq, __shfl_xor(mq, m, 32));
      float sum = 0.f;
#pragma unroll 8
      for (int q = 0; q < 32; ++q)
        sum += __expf(pu[t * 32 + q] + (pum[t * 32 + q] - 1.0f) * 1e15f + posn[q] - mq);
      D[row * 32 + t] = mq + __logf(sum);
    }
    return;
  }
  // ---- node split-K GEMM (float4 staging) ----
  float (*A)[132] = (float(*)[132])smem;
  float (*Wl)[32] = (float(*)[32])(smem + 8448);
  float* Wsl = smem + 12544;
  int rg = bid >> 2;
  int s = bid & 3;
  int row0 = rg * 64;
  int h0 = s * 256;
  int tr = t >> 3, tc = t & 7;
  int r0 = tr * 2;
  int c = tc * 4;
  float acc[8] = {0.f, 0.f, 0.f, 0.f, 0.f, 0.f, 0.f, 0.f};
  float sp0 = 0.f, sp1 = 0.f;
  for (int hc = 0; hc < 2; ++hc) {
    int hb = h0 + hc * 128;
#pragma unroll
    for (int k = 0; k < 8; ++k) {          // A: 64x128 f32 = 2048 float4
      int f = t + (k << 8);
      int rr = f >> 5, c4 = f & 31;
      *(float4*)&A[rr][c4 << 2] =
          *(const float4*)&ph[(row0 + rr) * 1024 + hb + (c4 << 2)];
    }
#pragma unroll
    for (int k = 0; k < 4; ++k) {          // W: 128x32 f32 = 1024 float4
      int f = t + (k << 8);
      int hh = f >> 3, c4 = f & 7;
      *(float4*)&Wl[hh][c4 << 2] =
          *(const float4*)&Wn[(hb + hh) * 32 + (c4 << 2)];
    }
    if (t < 128) Wsl[t] = Ws[hb + t];
    __syncthreads();
#pragma unroll 2
    for (int h = 0; h < 128; ++h) {
      float a0 = A[r0][h], a1 = A[r0 + 1][h];
      float4 w = *(const float4*)&Wl[h][c];
      acc[0] += a0 * w.x; acc[1] += a0 * w.y; acc[2] += a0 * w.z; acc[3] += a0 * w.w;
      acc[4] += a1 * w.x; acc[5] += a1 * w.y; acc[6] += a1 * w.z; acc[7] += a1 * w.w;
      if (tc == 0) { float wv = Wsl[h]; sp0 += a0 * wv; sp1 += a1 * wv; }
    }
    __syncthreads();
  }
  int row = row0 + r0;
  float* po = part + s * 262144;
  *(float4*)&po[row * 32 + c] = make_float4(acc[0], acc[1], acc[2], acc[3]);
  *(float4*)&po[(row + 1) * 32 + c] = make_float4(acc[4], acc[5], acc[6], acc[7]);
  if (tc == 0) {
    partS[s * 8192 + row] = sp0;
    partS[s * 8192 + row + 1] = sp1;
  }
}

__global__ __launch_bounds__(256) void k_node_reduce(
    const float* __restrict__ part, const float* __restrict__ partS,
    const float* __restrict__ bn, const float* __restrict__ bs,
    const float* __restrict__ D, float* __restrict__ node,
    float* __restrict__ cng, float* __restrict__ span) {
  int t = threadIdx.x;
  int row = blockIdx.x * 8 + (t >> 5);
  int c = t & 31;
  float v = bn[c];
#pragma unroll
  for (int s = 0; s < 4; ++s) v += part[s * 262144 + row * 32 + c];
  node[row * 32 + c] = v;
  int l = (row >> 5) & 31, m = row & 31;
  if (l == m)
    cng[row * 32 + c] = v + D[(row >> 5) * 32 + c] + v;   // chart_diag + node
  if (c == 0) {
    float sp = bs[0];
#pragma unroll
    for (int s = 0; s < 4; ++s) sp += partS[s * 8192 + row];
    span[row] = sp;
  }
}

// One block per batch; chart as NORMALIZED X = exp(cn - rowmax) in LDS
// (transposed [symbol][cellidx], stride 529). Per stage (4 barriers):
// [prefetch + P1] B [P2 both halves] B [P3] B [out+renorm fused] B
// LDS 160704 B:
//   Xt    f32[32*529]   @0
//   Sb    32 x 2052 B   @67712    (bf16 S, XOR-swizzled)
//   slots f32[4*1056]   @133376   (cell-major, stride 33)
//   T2    int2[32][32]  @150272
//   maxv  f32[528]      @158464
//   G     f32[32]       @160576
__global__ __launch_bounds__(1024) void k_chain6(
    const float* __restrict__ node, const float* __restrict__ span,
    const float* __restrict__ cng, const unsigned short* __restrict__ Rbf,
    const int* __restrict__ sm, const float* __restrict__ rootm,
    float* __restrict__ out) {
  extern __shared__ char lds[];
  float* Xt = (float*)lds;
  char* Sb = lds + 67712;
  float* slots = (float*)(lds + 133376);
  int2* T2 = (int2*)(lds + 150272);
  float* maxv = (float*)(lds + 158464);
  float* G = (float*)(lds + 160576);
  const int t = threadIdx.x;
  const int b = blockIdx.x;
  const int w = t >> 6, ln = t & 63;
  const int pq = ln & 31, hi = ln >> 5, jb = hi << 3;
  const int rowB = b * 32;

  // ---- zero-init Xt (NaN-proof: every readable slot finite) ----
  {
    int l = t >> 5, a = t & 31;
    float dv = cng[((rowB + l) * 32 + l) * 32 + a];   // diag prefetch overlaps
    float* z = (float*)lds;
    for (int idx = t; idx < 16928; idx += 1024) z[idx] = 0.f;
    __syncthreads();
    // ---- init: diagonal cells -> X, maxv ----
    float m = dv;
#pragma unroll
    for (int s = 16; s >= 1; s >>= 1) m = fmaxf(m, __shfl_xor(m, s, 32));
    int off = l * (65 - l) / 2;
    Xt[a * 529 + off] = __expf(dv - m);
    if (a == 0) maxv[off] = m;
  }
  __syncthreads();

  for (int i = 1; i < 32; ++i) {
    const int nT = 32 - i;
    // ---- out-phase operand prefetch (mapping: cell=t>>5, a=t&31) ----
    float nv = 0.f, sv = 0.f;
    {
      int cell = t >> 5;
      if (cell < nT) {
        nv = node[(rowB + cell) * 1024 + (cell + i) * 32 + (t & 31)];
        sv = span[(rowB + cell) * 32 + (cell + i)];
      }
    }
    // ---- P1: Tscl/rc tables + G ----
    {
      int c = t >> 5, j = t & 31;
      bool on = (c < nT) && (j < i);
      float gj = -3.0e38f; int rc = 0;
      if (on) {
        int m2 = c + j + 1;
        rc = m2 * (65 - m2) / 2 + (i - 1 - j);
        gj = maxv[c * (65 - c) / 2 + j] + maxv[rc];
      }
      float gm = gj;
#pragma unroll
      for (int s = 16; s >= 1; s >>= 1) gm = fmaxf(gm, __shfl_xor(gm, s, 32));
      if (c < nT) {
        float sc = on ? __expf(gj - gm) : 0.f;
        T2[(c << 5) + j] = make_int2(__float_as_int(sc), on ? rc : 0);
        if (j == 0) G[c] = gm;
      }
    }
    __syncthreads();
    // ---- P2: wave w -> cells w and 16+w; S = sum_j (scl*Xl) (x) Xr ----
#pragma unroll 1
    for (int half = 0; half < 2; ++half) {
      int cg = (half << 4) + w;
      if (cg >= nT) break;                 // wave-uniform
      const float* xlb = Xt + pq * 529 + cg * (65 - cg) / 2;
      const float* xrr = Xt + pq * 529;
      f32x16 Sacc = {};
#pragma unroll
      for (int kk = 0; kk < 2; ++kk) {
        if (kk == 1 && i <= 16) break;
        int j0 = (kk << 4);
        float xl[8], xr[8], sc[8];
#pragma unroll
        for (int r = 0; r < 8; ++r) {
          int2 e = T2[(cg << 5) + j0 + jb + r];
          sc[r] = __int_as_float(e.x);
          xr[r] = xrr[e.y];
          xl[r] = xlb[j0 + jb + r];
        }
        BFU ua, ub;
#pragma unroll
        for (int r2 = 0; r2 < 4; ++r2) {
          unsigned al = (unsigned short)f2bf(sc[2 * r2] * xl[2 * r2]);
          unsigned ah = (unsigned short)f2bf(sc[2 * r2 + 1] * xl[2 * r2 + 1]);
          ua.u[r2] = al | (ah << 16);
          unsigned bl = (unsigned short)f2bf(xr[2 * r2]);
          unsigned bh = (unsigned short)f2bf(xr[2 * r2 + 1]);
          ub.u[r2] = bl | (bh << 16);
        }
        Sacc = __builtin_amdgcn_mfma_f32_32x32x16_bf16(ua.v, ub.v, Sacc, 0, 0, 0);
      }
      // store S bf16, XOR-swizzled
      char* sbp = Sb + cg * 2052;
#pragma unroll
      for (int rr = 0; rr < 16; ++rr) {
        int p = (rr & 3) + ((rr >> 2) << 3) + (hi << 2);
        int wd = (((p << 4) + (pq >> 1)) ^ (((pq >> 3) & 1) << 4)) ^ (((p >> 2) & 1) << 2);
        *(unsigned short*)(sbp + wd * 4 + ((pq & 1) << 1)) = (unsigned short)f2bf(Sacc[rr]);
      }
    }
    __syncthreads();
    // ---- P3: inner = R * S, 32 cells wide, 4-wave k-split; ra loads inline ----
    if (w < 4) {
      f32x16 C0 = {}, C1 = {};
#pragma unroll
      for (int tt = 0; tt < 16; ++tt) {
        int kst = (w << 4) + tt;
        bf16x8 ra = *(const bf16x8*)(Rbf + (kst << 9) + (ln << 3));
        int ko = (kst << 1) + hi;
        int p = ko >> 2, o = ko & 3;
        int wd = (((p << 4) + (o << 2)) ^ ((o & 1) << 4)) ^ (((p >> 2) & 1) << 2);
        const char* sp = Sb + pq * 2052 + wd * 4;
        BFU ub;
        ub.u[0] = *(const unsigned*)sp;
        ub.u[1] = *(const unsigned*)(sp + 4);
        ub.u[2] = *(const unsigned*)(sp + 8);
        ub.u[3] = *(const unsigned*)(sp + 12);
        if (tt & 1) C1 = __builtin_amdgcn_mfma_f32_32x32x16_bf16(ra, ub.v, C1, 0, 0, 0);
        else        C0 = __builtin_amdgcn_mfma_f32_32x32x16_bf16(ra, ub.v, C0, 0, 0, 0);
      }
      // store cell-major (stride 33): value(lane,rr) = (a=arow, cell=pq)
      float* sl = slots + w * 1056;
#pragma unroll
      for (int rr = 0; rr < 16; ++rr) {
        int arow = (rr & 3) + ((rr >> 2) << 3) + (hi << 2);
        sl[pq * 33 + arow] = C0[rr] + C1[rr];
      }
    }
    __syncthreads();
    // ---- out + renorm fused: thread (cell=t>>5, a=t&31) ----
    {
      int cell = t >> 5, a = t & 31;
      if (cell < nT) {
        int so = cell * 33 + a;
        float pt = slots[so] + slots[1056 + so] + slots[2112 + so] + slots[3168 + so];
        float cnv = G[cell] + __logf(pt) + nv + nv + sv;   // chart + node
        float m = cnv;
#pragma unroll
        for (int s = 16; s >= 1; s >>= 1) m = fmaxf(m, __shfl_xor(m, s, 32));
        int ix = cell * (65 - cell) / 2 + i;
        Xt[a * 529 + ix] = __expf(cnv - m);
        if (a == 0) maxv[ix] = m;
      }
    }
    __syncthreads();
  }
  // ---- logits ----
  if (t < 32) {
    int len = 0;
#pragma unroll
    for (int l = 0; l < 32; ++l) len += sm[b * 32 + l];
    int e = len - 1;   // cell (0, e) has triangular index e
    float cv = maxv[e] + __logf(Xt[t * 529 + e]) - node[(rowB * 32 + e) * 32 + t];
    out[b * 32 + t] = cv + (rootm[t] - 1.0f) * 1e10f;
  }
}

extern "C" void kernel_launch(void* const* d_in, const int* in_sizes, int n_in,
                              void* d_out, int out_size, void* d_ws, size_t ws_size,
                              hipStream_t stream) {
  const float* ph    = (const float*)d_in[0];
  const float* sh    = (const float*)d_in[1];
  const int*   sm    = (const int*)  d_in[2];
  const float* Wp    = (const float*)d_in[3];
  const float* bp    = (const float*)d_in[4];
  const float* Wn    = (const float*)d_in[5];
  const float* bn    = (const float*)d_in[6];
  const float* Ws    = (const float*)d_in[7];
  const float* bs    = (const float*)d_in[8];
  const float* rs    = (const float*)d_in[9];
  const float* pu    = (const float*)d_in[10];
  const float* rootm = (const float*)d_in[11];
  const float* pm    = (const float*)d_in[12];
  const float* rm    = (const float*)d_in[13];
  const float* pum   = (const float*)d_in[14];
  float* out = (float*)d_out;

  float* ws    = (float*)d_ws;
  float* node  = ws + NODE_OFF;
  float* cng   = ws + CN_OFF;
  float* span  = ws + SPAN_OFF;
  float* D     = ws + D_OFF;
  unsigned short* Rbf = (unsigned short*)(ws + RBF_OFF);
  float* part  = ws + PART_OFF;
  float* partS = ws + PARTS_OFF;

  hipFuncSetAttribute((const void*)k_chain6,
                      hipFuncAttributeMaxDynamicSharedMemorySize, 160704);
  k_pre<<<896, 256, 0, stream>>>(ph, Wn, Ws, sh, Wp, bp, pm, pu, pum, rs, rm,
                                 part, partS, D, Rbf);
  k_node_reduce<<<1024, 256, 0, stream>>>(part, partS, bn, bs, D, node, cng, span);
  k_chain6<<<8, 1024, 160704, stream>>>(node, span, cng, Rbf, sm, rootm, out);
}